// Round 5
// baseline (2190.948 us; speedup 1.0000x reference)
//
#include <hip/hip_runtime.h>
#include <type_traits>

#define DEV __device__ __forceinline__

typedef _Float16 f16;
typedef __attribute__((ext_vector_type(8))) _Float16 f16x8;
typedef __attribute__((ext_vector_type(4))) float f32x4;

DEV int imin(int a, int b) { return a < b ? a : b; }

// LDS tile byte-swizzle: rows are 128B (64 f16); XOR row&7 into bits 4..6
DEV int swz(int row, int colByte) { return (row * 128 + colByte) ^ ((row & 7) << 4); }

// fp32 -> f16 hi/lo pair via v_cvt_pkrtz (hi RTZ; residual exact in f32; lo RTZ)
DEV void split2(float x, float y, unsigned& hi, unsigned& lo) {
  auto h = __builtin_amdgcn_cvt_pkrtz(x, y);
  auto l = __builtin_amdgcn_cvt_pkrtz(x - (float)h[0], y - (float)h[1]);
  hi = __builtin_bit_cast(unsigned, h);
  lo = __builtin_bit_cast(unsigned, l);
}
DEV void split4(const float4& n, uint2& hi, uint2& lo) {
  split2(n.x, n.y, hi.x, lo.x);
  split2(n.z, n.w, hi.y, lo.y);
}

struct GArgs {
  const void* A; const void* Alo;      // pair A planes (AM 0/5) or f32 (AM 1/4)
  const void* B; const void* Blo;      // BMD 0: pair planes; BMD 1/2: f32 in B
  const float* Hin; float* Hout;
  f16* O16; f16* O16lo;
  const int* perm; const int* off;
  int M, K, lda, ldb, ldo;
  long sAz, sBz, sOz;                  // per-z strides (elements)
  long zA, zB, zH;                     // per-K-chunk strides: bytes(A), bytes(B), elems(slab)
  int KS;                              // split-K factor (z = e*KS + kc)
};

// AM: 0=f16 pair [M][K]; 5=f16 pair + perm-gather; 1=f32 [M][K]; 4=f32 transpose (G[k][m])
// BMD: 0=f16 pair [N][K]; 1=f32 [K][N] (strided); 2=f32 [N][K]
// CM: 0=f16 pair store; 1=f32 Hout=acc(+Hin); 2=relu->f16 pair (guarded); 4=f32 partial slab
template<int TM,int TN,int WR,int WC,int AM,int BMD,int CM,bool RESID,bool EXPERT>
__global__ __launch_bounds__(256, 4)
void gk(GArgs a) {
  constexpr int TK = 64;
  constexpr int NT = 256;
  static_assert(WR * WC == 4, "4 waves per block");
  constexpr int WTM = TM / WR, WTN = TN / WC;
  constexpr int FM = WTM / 16, FN = WTN / 16;
  constexpr bool APAIR = (AM == 0 || AM == 5);
  constexpr int UA = APAIR ? (TM * (TK / 8)) / NT : (TM * (TK / 4)) / NT;
  constexpr int UB = (BMD == 0) ? (TN * (TK / 8)) / NT : (TN * (TK / 4)) / NT;

  __shared__ __align__(16) f16 As[2 * TM * TK];
  __shared__ __align__(16) f16 Bs[2 * TN * TK];
  __shared__ __align__(16) f16 AsL[2 * TM * TK];
  __shared__ __align__(16) f16 BsL[2 * TN * TK];

  const int tid = threadIdx.x;
  const int lane = tid & 63;
  const int wid = tid >> 6;
  const int wr = wid / WC, wc = wid % WC;

  int m0;
  int sEnd = 0x7fffffff;
  const char* Ab = (const char*)a.A;
  const char* AbL = (const char*)a.Alo;
  const char* Bb = (const char*)a.B;
  const char* BbL = (const char*)a.Blo;
  f16* O = a.O16;
  f16* OL = a.O16lo;
  float* HoutP = a.Hout;
  {
    int z = blockIdx.z;
    int e = z / a.KS;
    int kc = z - e * a.KS;
    if constexpr (EXPERT) {
      int o0 = a.off[e], o1 = a.off[e + 1];
      if ((int)blockIdx.y * TM >= o1 - o0) return;   // early-exit before any barrier
      m0 = o0 + blockIdx.y * TM;
      sEnd = o1;
      Bb += (long)e * a.sBz * 4 + (long)kc * a.zB;
      Ab += (long)kc * a.zA;
      AbL += (long)kc * a.zA;
    } else {
      m0 = blockIdx.y * TM;
      Ab += (long)e * a.sAz * 4 + (long)kc * a.zA;
      AbL += (long)kc * a.zA;
      Bb += (long)e * a.sBz * 4 + (long)kc * a.zB;
      if constexpr (CM == 0) {
        O += (long)e * a.sOz;
        OL += (long)e * a.sOz;
      }
    }
    if constexpr (CM == 4) HoutP += (long)kc * a.zH;
  }
  const int n0 = blockIdx.x * TN;

  int arow[UA];
  #pragma unroll
  for (int u = 0; u < UA; ++u) {
    int id = tid + u * NT;
    if constexpr (AM == 0) arow[u] = imin(m0 + (id >> 3), a.M - 1);
    else if constexpr (AM == 5) arow[u] = a.perm[imin(m0 + (id >> 3), a.M - 1)];
    else if constexpr (AM == 4) arow[u] = id % TM;   // local col in source
    else arow[u] = imin(m0 + (id >> 4), a.M - 1);
  }

  using ARt = typename std::conditional<APAIR, int4, float4>::type;
  using BRt = typename std::conditional<BMD == 0, int4, float4>::type;

  auto issueA = [&](ARt* rg, ARt* rl, int k0) {
    #pragma unroll
    for (int u = 0; u < UA; ++u) {
      int id = tid + u * NT;
      if constexpr (APAIR) {
        int kq = id & 7;
        long off = ((long)arow[u] * a.lda + k0 + kq * 8) * 2;
        rg[u] = *(const int4*)(Ab + off);
        rl[u] = *(const int4*)(AbL + off);
      } else if constexpr (AM == 4) {
        int kq = id / TM;
        const float* g = (const float*)Ab;
        #pragma unroll
        for (int i = 0; i < 4; ++i)
          ((float*)&rg[u])[i] = g[(long)(k0 + kq * 4 + i) * a.lda + (m0 + arow[u])];
      } else {
        int kq = id & 15;
        rg[u] = *(const float4*)(Ab + ((long)arow[u] * a.lda + k0 + kq * 4) * 4);
      }
    }
  };
  auto commitA = [&](ARt* rg, ARt* rl, int bi) {
    char* base = (char*)As + bi * (TM * 128);
    char* baseL = (char*)AsL + bi * (TM * 128);
    #pragma unroll
    for (int u = 0; u < UA; ++u) {
      int id = tid + u * NT;
      if constexpr (APAIR) {
        int m = id >> 3, kq = id & 7;
        *(int4*)(base + swz(m, kq * 16)) = rg[u];
        *(int4*)(baseL + swz(m, kq * 16)) = rl[u];
      } else {
        int m, kq;
        if constexpr (AM == 4) { m = id % TM; kq = id / TM; }
        else { m = id >> 4; kq = id & 15; }
        float4 v = *(float4*)&rg[u];
        uint2 ph, pl;
        split4(v, ph, pl);
        *(uint2*)(base + swz(m, kq * 8)) = ph;
        *(uint2*)(baseL + swz(m, kq * 8)) = pl;
      }
    }
  };
  auto issueB = [&](BRt* rg, BRt* rl, int k0) {
    #pragma unroll
    for (int u = 0; u < UB; ++u) {
      int id = tid + u * NT;
      if constexpr (BMD == 0) {
        int n = id >> 3, kq = id & 7;
        long off = ((long)(n0 + n) * a.ldb + k0 + kq * 8) * 2;
        rg[u] = *(const int4*)(Bb + off);
        rl[u] = *(const int4*)(BbL + off);
      } else if constexpr (BMD == 1) {
        int n = id % TN, kq = id / TN;
        const float* g = (const float*)Bb;
        #pragma unroll
        for (int i = 0; i < 4; ++i)
          ((float*)&rg[u])[i] = g[(long)(k0 + kq * 4 + i) * a.ldb + (n0 + n)];
      } else {
        int n = id >> 4, kq = id & 15;
        rg[u] = *(const float4*)(Bb + ((long)(n0 + n) * a.ldb + k0 + kq * 4) * 4);
      }
    }
  };
  auto commitB = [&](BRt* rg, BRt* rl, int bi) {
    char* base = (char*)Bs + bi * (TN * 128);
    char* baseL = (char*)BsL + bi * (TN * 128);
    #pragma unroll
    for (int u = 0; u < UB; ++u) {
      int id = tid + u * NT;
      if constexpr (BMD == 0) {
        int n = id >> 3, kq = id & 7;
        *(int4*)(base + swz(n, kq * 16)) = rg[u];
        *(int4*)(baseL + swz(n, kq * 16)) = rl[u];
      } else {
        int n, kq;
        if constexpr (BMD == 1) { n = id % TN; kq = id / TN; }
        else { n = id >> 4; kq = id & 15; }
        float4 v = *(float4*)&rg[u];
        uint2 ph, pl;
        split4(v, ph, pl);
        *(uint2*)(base + swz(n, kq * 8)) = ph;
        *(uint2*)(baseL + swz(n, kq * 8)) = pl;
      }
    }
  };

  f32x4 acc[FM][FN] = {};
  auto compute = [&](int bi) {
    const char* pA = (const char*)As + bi * (TM * 128);
    const char* pAL = (const char*)AsL + bi * (TM * 128);
    const char* pB = (const char*)Bs + bi * (TN * 128);
    const char* pBL = (const char*)BsL + bi * (TN * 128);
    #pragma unroll
    for (int kk = 0; kk < 2; ++kk) {
      const int col2 = (kk * 32 + (lane >> 4) * 8) * 2;
      f16x8 ah[FM], al[FM], bh[FN], bl[FN];
      #pragma unroll
      for (int i = 0; i < FM; ++i) {
        ah[i] = *(const f16x8*)(pA + swz(wr * WTM + i * 16 + (lane & 15), col2));
        al[i] = *(const f16x8*)(pAL + swz(wr * WTM + i * 16 + (lane & 15), col2));
      }
      #pragma unroll
      for (int j = 0; j < FN; ++j) {
        bh[j] = *(const f16x8*)(pB + swz(wc * WTN + j * 16 + (lane & 15), col2));
        bl[j] = *(const f16x8*)(pBL + swz(wc * WTN + j * 16 + (lane & 15), col2));
      }
      #pragma unroll
      for (int i = 0; i < FM; ++i)
        #pragma unroll
        for (int j = 0; j < FN; ++j) {
          f32x4 t = acc[i][j];
          t = __builtin_amdgcn_mfma_f32_16x16x32_f16(al[i], bh[j], t, 0, 0, 0);
          t = __builtin_amdgcn_mfma_f32_16x16x32_f16(ah[i], bl[j], t, 0, 0, 0);
          t = __builtin_amdgcn_mfma_f32_16x16x32_f16(ah[i], bh[j], t, 0, 0, 0);
          acc[i][j] = t;
        }
    }
  };

  // ---- main loop: 3 register sets (depth-2 prefetch), 2 LDS buffers, 1 barrier/step ----
  ARt ag0[UA], ag1[UA], ag2[UA], al0[UA], al1[UA], al2[UA];
  BRt bg0[UB], bg1[UB], bg2[UB], bl0[UB], bl1[UB], bl2[UB];
  const int ns = a.K / TK;
  issueA(ag0, al0, 0); issueB(bg0, bl0, 0);
  if (TK < a.K) { issueA(ag1, al1, TK); issueB(bg1, bl1, TK); }
  for (int s = 0; s < ns; s += 6) {
    int k;
    { commitA(ag0, al0, 0); commitB(bg0, bl0, 0);
      k = (s + 2) * TK; if (k < a.K) { issueA(ag2, al2, k); issueB(bg2, bl2, k); }
      __syncthreads(); compute(0); }
    if (s + 1 < ns) {
      commitA(ag1, al1, 1); commitB(bg1, bl1, 1);
      k = (s + 3) * TK; if (k < a.K) { issueA(ag0, al0, k); issueB(bg0, bl0, k); }
      __syncthreads(); compute(1); }
    if (s + 2 < ns) {
      commitA(ag2, al2, 0); commitB(bg2, bl2, 0);
      k = (s + 4) * TK; if (k < a.K) { issueA(ag1, al1, k); issueB(bg1, bl1, k); }
      __syncthreads(); compute(0); }
    if (s + 3 < ns) {
      commitA(ag0, al0, 1); commitB(bg0, bl0, 1);
      k = (s + 5) * TK; if (k < a.K) { issueA(ag2, al2, k); issueB(bg2, bl2, k); }
      __syncthreads(); compute(1); }
    if (s + 4 < ns) {
      commitA(ag1, al1, 0); commitB(bg1, bl1, 0);
      k = (s + 6) * TK; if (k < a.K) { issueA(ag0, al0, k); issueB(bg0, bl0, k); }
      __syncthreads(); compute(0); }
    if (s + 5 < ns) {
      commitA(ag2, al2, 1); commitB(bg2, bl2, 1);
      k = (s + 7) * TK; if (k < a.K) { issueA(ag1, al1, k); issueB(bg1, bl1, k); }
      __syncthreads(); compute(1); }
  }

  // ---- epilogue ----
  const int cr = (lane >> 4) * 4;
  const int cc = lane & 15;
  if constexpr (CM == 0 || CM == 2) {
    #pragma unroll
    for (int i = 0; i < FM; ++i) {
      #pragma unroll
      for (int r = 0; r < 4; ++r) {
        int gm = m0 + wr * WTM + i * 16 + cr + r;
        if (gm >= sEnd) continue;
        #pragma unroll
        for (int j = 0; j < FN; ++j) {
          int gn = n0 + wc * WTN + j * 16 + cc;
          float v = acc[i][j][r];
          if constexpr (CM == 2) v = fmaxf(v, 0.f);
          f16 hv = (f16)v;
          O[(long)gm * a.ldo + gn] = hv;
          OL[(long)gm * a.ldo + gn] = (f16)(v - (float)hv);
        }
      }
    }
  } else if constexpr (CM == 4) {
    #pragma unroll
    for (int i = 0; i < FM; ++i) {
      #pragma unroll
      for (int r = 0; r < 4; ++r) {
        int s = m0 + wr * WTM + i * 16 + cr + r;
        if (s >= sEnd || s >= a.M) continue;
        #pragma unroll
        for (int j = 0; j < FN; ++j) {
          int gn = n0 + wc * WTN + j * 16 + cc;
          HoutP[(long)s * a.ldo + gn] = acc[i][j][r];
        }
      }
    }
  } else {  // CM == 1
    #pragma unroll
    for (int i = 0; i < FM; ++i) {
      #pragma unroll
      for (int r = 0; r < 4; ++r) {
        int gm = m0 + wr * WTM + i * 16 + cr + r;
        #pragma unroll
        for (int j = 0; j < FN; ++j) {
          int gn = n0 + wc * WTN + j * 16 + cc;
          float v = acc[i][j][r];
          if constexpr (RESID) v += a.Hin[(long)gm * 768 + gn];
          a.Hout[(long)gm * 768 + gn] = v;
        }
      }
    }
  }
}

// ---- fin: sum NS slabs (+prob/bias/resid), write h (f32) + rmsnorm'd f16 pair ----
// wave per row; full-row sum-of-squares in-register (deterministic shfl tree)
template<int NS, bool PERM, bool PROB, bool RESID, bool BIAS, bool WRH>
__global__ __launch_bounds__(256)
void fin_k(const float* src, long sst, const int* perm, const float* prob,
           const float* Hin, const float* bias, float* Hout,
           const float* lnw, f16* nH, f16* nL) {
  const int lane = threadIdx.x & 63;
  const int s = blockIdx.x * 4 + (threadIdx.x >> 6);
  const int row = PERM ? perm[s] : s;
  const float p = PROB ? prob[row] : 1.f;
  float4 v[3];
  float ss = 0.f;
  #pragma unroll
  for (int j = 0; j < 3; ++j) {
    const int c = j * 256 + lane * 4;
    float4 t = *(const float4*)(src + (long)s * 768 + c);
    if constexpr (NS == 4) {
      const float4 t1 = *(const float4*)(src + sst + (long)s * 768 + c);
      const float4 t2 = *(const float4*)(src + 2 * sst + (long)s * 768 + c);
      const float4 t3 = *(const float4*)(src + 3 * sst + (long)s * 768 + c);
      t.x = (t.x + t1.x) + (t2.x + t3.x); t.y = (t.y + t1.y) + (t2.y + t3.y);
      t.z = (t.z + t1.z) + (t2.z + t3.z); t.w = (t.w + t1.w) + (t2.w + t3.w);
    }
    if constexpr (PROB) { t.x *= p; t.y *= p; t.z *= p; t.w *= p; }
    if constexpr (BIAS) {
      const float4 b = *(const float4*)(bias + c);
      t.x += b.x; t.y += b.y; t.z += b.z; t.w += b.w;
    }
    if constexpr (RESID) {
      const float4 h = *(const float4*)(Hin + (long)row * 768 + c);
      t.x += h.x; t.y += h.y; t.z += h.z; t.w += h.w;
    }
    v[j] = t;
    ss += t.x * t.x + t.y * t.y + t.z * t.z + t.w * t.w;
  }
  #pragma unroll
  for (int m = 1; m < 64; m <<= 1) ss += __shfl_xor(ss, m);
  const float rr = rsqrtf(ss * (1.f / 768.f) + 1e-6f);
  #pragma unroll
  for (int j = 0; j < 3; ++j) {
    const int c = j * 256 + lane * 4;
    if constexpr (WRH) *(float4*)(Hout + (long)row * 768 + c) = v[j];
    const float4 w = *(const float4*)(lnw + c);
    float4 n;
    n.x = v[j].x * rr * w.x; n.y = v[j].y * rr * w.y;
    n.z = v[j].z * rr * w.z; n.w = v[j].w * rr * w.w;
    uint2 hi, lo;
    split4(n, hi, lo);
    *(uint2*)((char*)nH + ((long)row * 768 + c) * 2) = hi;
    *(uint2*)((char*)nL + ((long)row * 768 + c) * 2) = lo;
  }
}

// ---- router: one wave per row, reads pre-normalized pair ----
__global__ __launch_bounds__(256)
void router_k(const f16* nH, const f16* nL, const float* rw, int* eid, float* prob) {
  int lane = threadIdx.x & 63;
  int row = blockIdx.x * 4 + (threadIdx.x >> 6);
  float le[8] = {0, 0, 0, 0, 0, 0, 0, 0};
  #pragma unroll
  for (int i = 0; i < 12; ++i) {
    int k = i * 64 + lane;
    float n = (float)nH[(long)row * 768 + k] + (float)nL[(long)row * 768 + k];
    const float* w = rw + k * 8;
    float4 w0 = *(const float4*)w, w1 = *(const float4*)(w + 4);
    le[0] += n * w0.x; le[1] += n * w0.y; le[2] += n * w0.z; le[3] += n * w0.w;
    le[4] += n * w1.x; le[5] += n * w1.y; le[6] += n * w1.z; le[7] += n * w1.w;
  }
  #pragma unroll
  for (int m = 1; m < 64; m <<= 1) {
    #pragma unroll
    for (int e = 0; e < 8; ++e) le[e] += __shfl_xor(le[e], m);
  }
  float mx = le[0]; int am = 0;
  #pragma unroll
  for (int e = 1; e < 8; ++e) if (le[e] > mx) { mx = le[e]; am = e; }
  float den = 0.f;
  #pragma unroll
  for (int e = 0; e < 8; ++e) den += expf(le[e] - mx);
  if (lane == 0) { eid[row] = am; prob[row] = 1.f / den; }
}

__global__ __launch_bounds__(256)
void scan_k(const int* eid, int* off, int* perm) {
  __shared__ int cnt[8], c2[8], offs[9];
  int tid = threadIdx.x;
  if (tid < 8) { cnt[tid] = 0; c2[tid] = 0; }
  __syncthreads();
  for (int t = tid; t < 1024; t += 256) atomicAdd(&cnt[eid[t]], 1);
  __syncthreads();
  if (tid == 0) {
    int acc = 0;
    for (int e = 0; e < 8; ++e) { offs[e] = acc; acc += cnt[e]; }
    offs[8] = acc;
    for (int e = 0; e < 9; ++e) off[e] = offs[e];
  }
  __syncthreads();
  for (int t = tid; t < 1024; t += 256) {
    int e = eid[t];
    int r = atomicAdd(&c2[e], 1);
    perm[offs[e] + r] = t;
  }
}

// ---- final fc on pre-normalized pair ----
__global__ __launch_bounds__(256)
void fc_k(const f16* nH, const f16* nL, const float* fw, const float* fb, float* out) {
  int lane = threadIdx.x & 63;
  int row = blockIdx.x * 4 + (threadIdx.x >> 6);
  float acc[10] = {0, 0, 0, 0, 0, 0, 0, 0, 0, 0};
  #pragma unroll
  for (int i = 0; i < 12; ++i) {
    int k = i * 64 + lane;
    float n = (float)nH[(long)row * 768 + k] + (float)nL[(long)row * 768 + k];
    const float* w = fw + k * 10;
    #pragma unroll
    for (int c = 0; c < 10; ++c) acc[c] += n * w[c];
  }
  #pragma unroll
  for (int m = 1; m < 64; m <<= 1) {
    #pragma unroll
    for (int c = 0; c < 10; ++c) acc[c] += __shfl_xor(acc[c], m);
  }
  if (lane == 0) {
    #pragma unroll
    for (int c = 0; c < 10; ++c) out[row * 10 + c] = acc[c] + fb[c];
  }
}

extern "C" void kernel_launch(void* const* d_in, const int* in_sizes, int n_in,
                              void* d_out, int out_size, void* d_ws, size_t ws_size,
                              hipStream_t stream) {
  const float* x     = (const float*)d_in[0];
  const float* projw = (const float*)d_in[1];
  const float* projb = (const float*)d_in[2];
  const float* ln1   = (const float*)d_in[3];
  const float* wvp   = (const float*)d_in[4];
  const float* wop   = (const float*)d_in[5];
  const float* ln2   = (const float*)d_in[6];
  const float* dwi   = (const float*)d_in[7];
  const float* dwo   = (const float*)d_in[8];
  const float* rw    = (const float*)d_in[9];
  const float* ewi   = (const float*)d_in[10];
  const float* ewo   = (const float*)d_in[11];
  const float* flnw  = (const float*)d_in[12];
  const float* fcw   = (const float*)d_in[13];
  const float* fcb   = (const float*)d_in[14];

  char* ws = (char*)d_ws;
  float* hA   = (float*)(ws);                        //  3,145,728
  float* hB   = (float*)(ws + 3145728);              //  3,145,728
  f16*   hidH = (f16*)(ws + 6291456);                //  6,291,456
  f16*   hidL = (f16*)(ws + 12582912);               //  6,291,456
  f16*   n2H  = (f16*)(ws + 18874368);               //  1,572,864
  f16*   n2L  = (f16*)(ws + 20447232);               //  1,572,864
  float* slab = (float*)(ws + 22020096);             // 12,582,912
  int*   eid  = (int*)(ws + 34603008);
  float* prob = (float*)(ws + 34607104);
  int*   perm = (int*)(ws + 34611200);
  int*   off  = (int*)(ws + 34615296);
  f16*   wctH = (f16*)(ws + 34615360);               // 14,155,776
  f16*   wctL = (f16*)(ws + 48771136);               // 14,155,776 -> end 62,926,912
  if (ws_size < 34615360u) return;
  const bool useWct = ws_size >= 62926912u;
  // n1 pair aliases the (dead-at-that-time) head of hid; mid pair for fallback attn
  f16* n1H = hidH;               f16* n1L = hidL;
  f16* midH = hidH + 786432;     f16* midL = hidL + 786432;
  const long SST = 1024 * 768;

  if (useWct) {  // Wc^T[l] = (wv@wo)^T as f16 pair: wct[l][n][k]
    GArgs g{}; g.A = wop; g.B = wvp; g.O16 = wctH; g.O16lo = wctL; g.KS = 1;
    g.M = 768; g.K = 768; g.lda = 768; g.ldb = 768; g.ldo = 768;
    g.sAz = 589824; g.sBz = 589824; g.sOz = 589824;
    gk<32,64,2,2, 4,2,0, false,false><<<dim3(12,24,12), 256, 0, stream>>>(g);
  }
  { // proj split-K=4 -> slab; fin adds bias, writes hA + ln1[0]-normed pair
    GArgs g{}; g.A = x; g.B = projw; g.Hout = slab; g.KS = 4;
    g.M = 1024; g.K = 768; g.lda = 3072; g.ldb = 768; g.ldo = 768;
    g.zA = 768 * 4; g.zB = (long)768 * 768 * 4; g.zH = SST;
    gk<32,64,2,2, 1,1,4, false,false><<<dim3(12,32,4), 256, 0, stream>>>(g);
    fin_k<4,false,false,false,true,true><<<dim3(256), 256, 0, stream>>>(
        slab, SST, nullptr, nullptr, nullptr, projb, hA, ln1, n1H, n1L);
  }
  for (int l = 0; l < 12; ++l) {
    const float* lnNext = (l < 11) ? ln1 + (l + 1) * 768 : flnw;
    if (useWct) { // attn: hB = hA + n1 @ Wc[l]   (pure pair GEMM)
      GArgs g{}; g.A = n1H; g.Alo = n1L; g.B = wctH + (long)l * 589824; g.Blo = wctL + (long)l * 589824;
      g.Hin = hA; g.Hout = hB; g.KS = 1;
      g.M = 1024; g.K = 768; g.lda = 768; g.ldb = 768; g.ldo = 768;
      gk<32,32,2,2, 0,0,1, true,false><<<dim3(24,32,1), 256, 0, stream>>>(g);
    } else {
      { // mid = n1 @ wv
        GArgs g{}; g.A = n1H; g.Alo = n1L; g.B = wvp + (long)l * 589824;
        g.O16 = midH; g.O16lo = midL; g.KS = 1;
        g.M = 1024; g.K = 768; g.lda = 768; g.ldb = 768; g.ldo = 768;
        gk<32,64,2,2, 0,1,0, false,false><<<dim3(12,32,1), 256, 0, stream>>>(g);
      }
      { // hB = hA + mid @ wo
        GArgs g{}; g.A = midH; g.Alo = midL; g.B = wop + (long)l * 589824;
        g.Hin = hA; g.Hout = hB; g.KS = 1;
        g.M = 1024; g.K = 768; g.lda = 768; g.ldb = 768; g.ldo = 768;
        gk<32,64,2,2, 0,1,1, true,false><<<dim3(12,32,1), 256, 0, stream>>>(g);
      }
    }
    // n2 = rmsnorm(hB, ln2[l]) as pair
    fin_k<1,false,false,false,false,false><<<dim3(256), 256, 0, stream>>>(
        hB, 0, nullptr, nullptr, nullptr, nullptr, nullptr, ln2 + l * 768, n2H, n2L);
    if ((l & 1) == 0) {
      int di = l / 2;
      { // ffn1: hid = relu(n2 @ dwi) pair
        GArgs g{}; g.A = n2H; g.Alo = n2L; g.B = dwi + (long)di * 768 * 3072;
        g.O16 = hidH; g.O16lo = hidL; g.KS = 1;
        g.M = 1024; g.K = 768; g.lda = 768; g.ldb = 3072; g.ldo = 3072;
        gk<32,64,2,2, 0,1,2, false,false><<<dim3(48,32,1), 256, 0, stream>>>(g);
      }
      { // ffn2 split-K=4 -> slab; fin: hA = hB + sum, + next-ln pair
        GArgs g{}; g.A = hidH; g.Alo = hidL; g.B = dwo + (long)di * 3072 * 768;
        g.Hout = slab; g.KS = 4;
        g.M = 1024; g.K = 768; g.lda = 3072; g.ldb = 768; g.ldo = 768;
        g.zA = 768 * 2; g.zB = (long)768 * 768 * 4; g.zH = SST;
        gk<32,64,2,2, 0,1,4, false,false><<<dim3(12,32,4), 256, 0, stream>>>(g);
        fin_k<4,false,false,true,false,true><<<dim3(256), 256, 0, stream>>>(
            slab, SST, nullptr, nullptr, hB, nullptr, hA, lnNext, n1H, n1L);
      }
    } else {
      int mi = l / 2;
      router_k<<<dim3(256), 256, 0, stream>>>(n2H, n2L, rw + (long)mi * 768 * 8, eid, prob);
      scan_k<<<dim3(1), 256, 0, stream>>>(eid, off, perm);
      { // egemm1: hid[slot] = relu(n2[perm[slot]] @ ewi[e]) pair
        GArgs g{}; g.A = n2H; g.Alo = n2L; g.B = ewi + (long)mi * 8 * 768 * 3072;
        g.O16 = hidH; g.O16lo = hidL; g.perm = perm; g.off = off; g.KS = 1;
        g.M = 1024; g.K = 768; g.lda = 768; g.ldb = 3072; g.ldo = 3072;
        g.sBz = (long)768 * 3072;
        gk<64,32,2,2, 5,1,2, false,true><<<dim3(96,16,8), 256, 0, stream>>>(g);
      }
      { // egemm2 split-K=4: slab[kc][slot] = hid[slot,kc] @ ewo[e][kc,:]
        GArgs g{}; g.A = hidH; g.Alo = hidL; g.B = ewo + (long)mi * 8 * 3072 * 768;
        g.Hout = slab; g.off = off; g.KS = 4;
        g.M = 1024; g.K = 768; g.lda = 3072; g.ldb = 768; g.ldo = 768;
        g.sBz = (long)3072 * 768; g.zA = 768 * 2; g.zB = (long)768 * 768 * 4; g.zH = SST;
        gk<32,64,2,2, 0,1,4, false,true><<<dim3(12,32,32), 256, 0, stream>>>(g);
        fin_k<4,true,true,true,false,true><<<dim3(256), 256, 0, stream>>>(
            slab, SST, perm, prob, hB, nullptr, hA, lnNext, n1H, n1L);
      }
    }
  }
  fc_k<<<dim3(256), 256, 0, stream>>>(n1H, n1L, fcw, fcb, (float*)d_out);
}